// Round 15
// baseline (1819.526 us; speedup 1.0000x reference)
//
#include <hip/hip_runtime.h>
#include <hip/hip_bf16.h>

#define DMdl 512
#define DIn  1024
#define DSn  16
#define DRn  32
#define NLa  4
#define BSz  16
#define LSq  200
#define CCl  200
#define MROWS (BSz*LSq)   // 3200
#define TCH  50           // scan chunk length (200 = 4*50)
#define NBLK 512          // persistent grid: 2 blocks/CU guaranteed co-resident

typedef __hip_bfloat16 bf16;
typedef unsigned short ushort;
typedef unsigned int uint;
typedef short short8 __attribute__((ext_vector_type(8)));
typedef short s16x4 __attribute__((ext_vector_type(4)));
typedef float f32x4 __attribute__((ext_vector_type(4)));

__device__ __forceinline__ float b2f(bf16 v) { return __bfloat162float(v); }
__device__ __forceinline__ short f2s(float v) {
  bf16 h = __float2bfloat16(v);
  return *reinterpret_cast<short*>(&h);
}
__device__ __forceinline__ float lo_f(uint v) { return __uint_as_float(v << 16); }
__device__ __forceinline__ float hi_f(uint v) { return __uint_as_float(v & 0xFFFF0000u); }
__device__ __forceinline__ uint bbits(float v) { return (uint)(ushort)f2s(v); }

#if __has_builtin(__builtin_amdgcn_exp2f)
#define EXP2F(x) __builtin_amdgcn_exp2f(x)
#else
#define EXP2F(x) __expf((x) * 0.6931471805599453f)
#endif

template<int CTRL>
__device__ __forceinline__ float dpp_add(float c) {
  int t = __builtin_amdgcn_update_dpp(0, __float_as_int(c), CTRL, 0xF, 0xF, true);
  return c + __int_as_float(t);
}

__device__ __forceinline__ bool probe_is_f32(const void* lnw) {
  const unsigned short* p = (const unsigned short*)lnw;
  return (p[0] == 0) && (p[2] == 0);
}
__device__ __forceinline__ float ld_in(const void* p, int i, bool f32) {
  return f32 ? ((const float*)p)[i] : b2f(((const bf16*)p)[i]);
}

// ---- fp32 small arena offsets (floats) ----
#define F_X     0
#define F_WE    6400
#define F_BE    7424
#define F_LNW   7936
#define F_LNB   9984
#define F_CW    12032
#define F_CB    28416
#define F_BDT   32512
#define F_ALOG  36608
#define F_D     102144
#define F_FNW   106240
#define F_FNB   106752
#define F_TOT   107264

__device__ const int f_off[13] = {F_X,F_WE,F_BE,F_LNW,F_LNB,F_CW,F_CB,F_BDT,
                                  F_ALOG,F_D,F_FNW,F_FNB,F_TOT};

// ---- bf16 weight arena offsets (shorts) ----
#define B_WIN    0              // 4 x 2048 x 512
#define B_WXP    4194304        // 4 x 64 x 1024
#define B_WDT    4456448        // 4 x 1024 x 32
#define B_WOUT   4587520        // 4 x 512 x 1024
#define B_WHEAD  6684672        // 200 x 512
#define B_TOT    6787072

#define CVT_SMALL_BLK 419       // F_TOT/256
#define CVT_WB_BLK    6628      // B_TOT/1024  (4 shorts per thread)

// grid-barrier counter: device global, zeroed by k_convert each replay
__device__ uint g_bar;

// ---------------- merged convert: small tensors -> fp32, weights -> bf16 ----------------
__global__ __launch_bounds__(256) void k_convert(
    const void* p0, const void* p1, const void* p2, const void* p3,
    const void* p4, const void* p6, const void* p7, const void* p10,
    const void* p11, const void* p12, const void* p14, const void* p15,
    const void* w5, const void* w8, const void* w9, const void* w13,
    const void* w16, float* __restrict__ fsA, short* __restrict__ wb) {
  if (blockIdx.x == 0 && threadIdx.x == 0) g_bar = 0;
  bool f32 = probe_is_f32(p3);
  if (blockIdx.x < CVT_SMALL_BLK) {
    const void* ps[12] = {p0,p1,p2,p3,p4,p6,p7,p10,p11,p12,p14,p15};
    int idx = blockIdx.x * 256 + threadIdx.x;
    int t = 0;
    while (idx >= f_off[t + 1]) ++t;
    fsA[idx] = ld_in(ps[t], idx - f_off[t], f32);
  } else {
    int idx = ((blockIdx.x - CVT_SMALL_BLK) * 256 + threadIdx.x) * 4;
    const void* src; int rel;
    if (idx < B_WXP)        { src = w5;  rel = idx; }
    else if (idx < B_WDT)   { src = w8;  rel = idx - B_WXP; }
    else if (idx < B_WOUT)  { src = w9;  rel = idx - B_WDT; }
    else if (idx < B_WHEAD) { src = w13; rel = idx - B_WOUT; }
    else                    { src = w16; rel = idx - B_WHEAD; }
    s16x4 o;
    if (f32) {
      f32x4 v = *(const f32x4*)((const float*)src + rel);
      o[0] = f2s(v[0]); o[1] = f2s(v[1]); o[2] = f2s(v[2]); o[3] = f2s(v[3]);
    } else {
      o = *(const s16x4*)((const short*)src + rel);
    }
    *(s16x4*)&wb[idx] = o;
  }
}

// ---------------- shared-memory union for the megakernel ----------------
struct ScanSmem {                       // 40,768 B
  float sBC[2][TCH * 36];
  float sTD[2][TCH * 34];
  uint  sUZ[2][TCH * 18];
  float sY [TCH * 16];
  float sXs[4 * 4 * 36];
  float sD [16];
};
struct GemmSmem {                       // 49,152 B (BJ=2 tiles: Bs 128 rows)
  short As[2][64 * 64];
  short Bs[2][128 * 64];
};
union MegaSmem {
  ScanSmem s;
  GemmSmem g;
  float nsh[8];
};

// ---------------- grid barrier: monotonic counter, thread-0 spin ----------------
__device__ __forceinline__ void grid_bar(int& ph) {
  __syncthreads();
  if (threadIdx.x == 0) {
    __threadfence();                               // release: drain + writeback
    __hip_atomic_fetch_add(&g_bar, 1u, __ATOMIC_RELAXED, __HIP_MEMORY_SCOPE_AGENT);
    ph += NBLK;
    while ((int)__hip_atomic_load(&g_bar, __ATOMIC_RELAXED, __HIP_MEMORY_SCOPE_AGENT) < ph)
      __builtin_amdgcn_s_sleep(8);
    __threadfence();                               // acquire: invalidate caches
  }
  __syncthreads();
}

// ---------------- block reduce (norm) ----------------
__device__ __forceinline__ float block_sum(float v, float* sh) {
  #pragma unroll
  for (int o = 32; o > 0; o >>= 1) v += __shfl_down(v, o, 64);
  int t = threadIdx.x;
  if ((t & 63) == 0) sh[t >> 6] = v;
  __syncthreads();
  if (t == 0) sh[4] = sh[0] + sh[1] + sh[2] + sh[3];
  __syncthreads();
  return sh[4];
}

// ---------------- residual add + LN/RMS for one row ----------------
__device__ __forceinline__ void norm_row(int row, const float* hin,
    const float* hin2, float* res, bf16* out, const float* w, const float* b,
    const float* fA, int first, int rms, int embed, float* sh) {
  int t = threadIdx.x;
  const float* hp  = hin  + (size_t)row * DMdl;
  const float* hp2 = hin2 + (size_t)row * DMdl;
  float* rp = res + (size_t)row * DMdl;
  float v0, v1;
  if (embed) {
    float x0 = fA[F_X + row * 2], x1 = fA[F_X + row * 2 + 1];
    v0 = x0 * fA[F_WE + t * 2] + x1 * fA[F_WE + t * 2 + 1] + fA[F_BE + t];
    v1 = x0 * fA[F_WE + (t + 256) * 2] + x1 * fA[F_WE + (t + 256) * 2 + 1]
         + fA[F_BE + t + 256];
  } else {
    v0 = hp[t] + hp2[t];
    v1 = hp[t + 256] + hp2[t + 256];
  }
  if (!first) { v0 += rp[t]; v1 += rp[t + 256]; }
  rp[t] = v0; rp[t + 256] = v1;
  float mean = 0.f;
  if (!rms) mean = block_sum(v0 + v1, sh) * (1.f / DMdl);
  float d0 = v0 - mean, d1 = v1 - mean;
  float var = block_sum(d0 * d0 + d1 * d1, sh) * (1.f / DMdl);
  float inv = rsqrtf(var + 1e-5f);
  bf16* op = out + (size_t)row * DMdl;
  op[t]       = __float2bfloat16(d0 * inv * w[t]       + b[t]);
  op[t + 256] = __float2bfloat16(d1 * inv * w[t + 256] + b[t + 256]);
}

// ---------------- async 16B global->LDS ----------------
__device__ __forceinline__ void async16(const short* g, short* l) {
  __builtin_amdgcn_global_load_lds(
      (const __attribute__((address_space(1))) void*)g,
      (__attribute__((address_space(3))) void*)l, 16, 0, 0);
}

// ---------------- one 64x(64*BJ) GEMM tile: C = A(M,K)*B(N,K)^T, BK=64 ----------------
// OM=0: f32 atomicAdd. OM=1: probe f32/bf16. OM=3: split bf16 (xc | silu->z).
// OM=4: f32 store to (dsel ? C2 : C).
template<int OM, int BJ>
__device__ __forceinline__ void gemm_tile(const short* __restrict__ A,
    const short* __restrict__ Bw, void* __restrict__ C, void* __restrict__ C2,
    int N, int Kst, int kLen, int kBeg, int bm, int bn, int act_col, int dsel,
    bool f32o, GemmSmem* g) {
  constexpr int NBCH = BJ * 2;          // B async16 per thread (BN = 64*BJ)
  int t = threadIdx.x;
  int lane = t & 63;
  int wn = t >> 6;
  const short* gA[2]; int loA[2];
  const short* gB[NBCH]; int loB[NBCH];
  #pragma unroll
  for (int q = 0; q < 2; ++q) {
    int ci = t + 256 * q; int r = ci >> 3; int sl = ci & 7;
    int cs = ((sl & 3) ^ (r & 3) ^ ((r >> 2) & 3)) | (sl & 4);
    loA[q] = ci * 8;
    gA[q] = A + (size_t)(bm + r) * Kst + kBeg + cs * 8;
  }
  #pragma unroll
  for (int q = 0; q < NBCH; ++q) {
    int ci = t + 256 * q; int r = ci >> 3; int sl = ci & 7;
    int cs = ((sl & 3) ^ (r & 3) ^ ((r >> 2) & 3)) | (sl & 4);
    loB[q] = ci * 8;
    int rb = bn + r; if (rb >= N) rb = N - 1;
    gB[q] = Bw + (size_t)rb * Kst + kBeg + cs * 8;
  }
  f32x4 acc[4][BJ];
  #pragma unroll
  for (int i = 0; i < 4; ++i)
    #pragma unroll
    for (int j = 0; j < BJ; ++j) acc[i][j] = (f32x4){0.f, 0.f, 0.f, 0.f};
  int quad = lane >> 4, r15 = lane & 15;
  int slot = quad ^ (r15 & 3) ^ ((r15 >> 2) & 3);
  int nIter = kLen >> 6;
  #pragma unroll
  for (int q = 0; q < 2; ++q)    { async16(gA[q], &g->As[0][loA[q]]); gA[q] += 64; }
  #pragma unroll
  for (int q = 0; q < NBCH; ++q) { async16(gB[q], &g->Bs[0][loB[q]]); gB[q] += 64; }
  for (int it = 0; it < nIter; ++it) {
    int cur = it & 1, nxt = cur ^ 1;
    __syncthreads();
    if (it + 1 < nIter) {
      #pragma unroll
      for (int q = 0; q < 2; ++q)    { async16(gA[q], &g->As[nxt][loA[q]]); gA[q] += 64; }
      #pragma unroll
      for (int q = 0; q < NBCH; ++q) { async16(gB[q], &g->Bs[nxt][loB[q]]); gB[q] += 64; }
    }
    #pragma unroll
    for (int kk = 0; kk < 2; ++kk) {
      short8 af[4], bfv[BJ];
      #pragma unroll
      for (int i = 0; i < 4; ++i)
        af[i] = *(const short8*)&g->As[cur][(i * 16 + r15) * 64 + kk * 32 + slot * 8];
      #pragma unroll
      for (int j = 0; j < BJ; ++j)
        bfv[j] = *(const short8*)&g->Bs[cur][(wn * (16 * BJ) + j * 16 + r15) * 64 + kk * 32 + slot * 8];
      #pragma unroll
      for (int i = 0; i < 4; ++i)
        #pragma unroll
        for (int j = 0; j < BJ; ++j)
          acc[i][j] = __builtin_amdgcn_mfma_f32_16x16x32_bf16(af[i], bfv[j], acc[i][j], 0, 0, 0);
    }
  }
  #pragma unroll
  for (int i = 0; i < 4; ++i) {
    int m0 = bm + i * 16 + quad * 4;
    #pragma unroll
    for (int j = 0; j < BJ; ++j) {
      int n = bn + wn * (16 * BJ) + j * 16 + r15;
      if (n >= N) continue;
      #pragma unroll
      for (int r = 0; r < 4; ++r) {
        float v = acc[i][j][r];
        size_t mrow = (size_t)(m0 + r);
        if (OM == 3) {
          if (n < act_col) {
            ((bf16*)C)[mrow * act_col + n] = __float2bfloat16(v);
          } else {
            v = v / (1.f + __expf(-v));
            ((bf16*)C2)[mrow * act_col + (n - act_col)] = __float2bfloat16(v);
          }
        } else {
          size_t off = mrow * N + n;
          if (OM == 4) { float* dst = dsel ? (float*)C2 : (float*)C; dst[off] = v; }
          else if (OM == 0) atomicAdd((float*)C + off, v);
          else if (OM == 1 && !f32o) ((bf16*)C)[off] = __float2bfloat16(v);
          else ((float*)C)[off] = v;
        }
      }
    }
  }
  __syncthreads();   // LDS safe for next tile / next phase
}

// ---------------- selective scan unit (r13 parity version) ----------------
__device__ void scan_block(ScanSmem* S, int L, const float* __restrict__ xdb,
    const ushort* __restrict__ u, const ushort* __restrict__ z,
    const short* __restrict__ wdt, const float* __restrict__ fA, int lay,
    bf16* __restrict__ y) {
  int tid  = threadIdx.x;
  int wave = tid >> 6;
  int lane = tid & 63;
  int chp  = tid & 15;
  int rg   = lane >> 4;
  int xcd = L & 7, w = L >> 3;
  int dblk = xcd * 8 + (w & 7);
  int bb = w >> 3;
  int d0 = dblk * 16;
  int cpair = (int)(L & 1);
  int isCons = ((wave >> 1) == cpair);
  int cw = wave & 1;
  if (tid < 16) S->sD[tid] = fA[F_D + lay * DIn + d0 + tid];
  float wf[DRn];
  {
    const uint* wp = (const uint*)(wdt + (size_t)lay * (DIn * DRn) + (d0 + chp) * DRn);
    #pragma unroll
    for (int k = 0; k < 16; ++k) {
      uint wv = wp[k];
      wf[2 * k] = lo_f(wv); wf[2 * k + 1] = hi_f(wv);
    }
  }
  float bd = fA[F_BDT + lay * DIn + d0 + chp];

  int ch = ((cw << 6) + lane) >> 3;
  int sg = lane & 7;
  float hst0 = 0.f, hst1 = 0.f;
  float Ac2x = 0.f, Ac2y = 0.f;
  if (isCons) {
    float2 al = *(const float2*)&fA[F_ALOG + lay * DIn * DSn + (d0 + ch) * DSn + 2 * sg];
    Ac2x = -__expf(al.x) * 1.44269504f;
    Ac2y = -__expf(al.y) * 1.44269504f;
  }

  float* xs = &S->sXs[wave * 4 * 36];

  auto produce = [&](int cc, int bi, int pw, int npw) {
    int row0 = bb * LSq + cc * TCH;
    float2 xdR[7], xbcR[7]; uint uzR[7];
    #pragma unroll
    for (int k = 0; k < 7; ++k) {
      int g = pw + k * npw;
      int s = g * 4 + rg;
      if (g < (TCH + 3) / 4 && s < TCH) {
        int row = row0 + s;
        xdR[k]  = *(const float2*)&xdb[(size_t)row * 64 + 2 * chp];
        xbcR[k] = *(const float2*)&xdb[(size_t)row * 64 + 32 + 2 * chp];
        if (chp < 8) uzR[k] = *(const uint*)&u[(size_t)row * DIn + d0 + 2 * chp];
        else         uzR[k] = *(const uint*)&z[(size_t)row * DIn + d0 + 2 * (chp - 8)];
      }
    }
    #pragma unroll
    for (int k = 0; k < 7; ++k) {
      int g = pw + k * npw;
      int s = g * 4 + rg;
      if (g < (TCH + 3) / 4 && s < TCH) {
        *(float2*)&xs[rg * 36 + 2 * chp]        = xdR[k];
        *(float2*)&S->sBC[bi][s * 36 + 2 * chp] = xbcR[k];
        S->sUZ[bi][s * 18 + chp] = uzR[k];
        asm volatile("s_waitcnt lgkmcnt(0)" ::: "memory");
        const f32x4* xr = (const f32x4*)&xs[rg * 36];
        float acc = bd;
        #pragma unroll
        for (int r4 = 0; r4 < 8; ++r4) {
          f32x4 xv = xr[r4];
          acc = fmaf(wf[4 * r4 + 0], xv[0], acc);
          acc = fmaf(wf[4 * r4 + 1], xv[1], acc);
          acc = fmaf(wf[4 * r4 + 2], xv[2], acc);
          acc = fmaf(wf[4 * r4 + 3], xv[3], acc);
        }
        float dtv = (acc > 15.f) ? acc : __logf(1.f + __expf(acc));
        uint up = S->sUZ[bi][s * 18 + (chp >> 1)];
        float uvf = (chp & 1) ? hi_f(up) : lo_f(up);
        *(float2*)&S->sTD[bi][s * 34 + 2 * chp] = make_float2(dtv, dtv * uvf);
      }
    }
  };

  produce(0, 0, wave, 4);
  __syncthreads();
  for (int c = 0; c < LSq / TCH; ++c) {
    int bi = c & 1;
    if (isCons) {
      const float* bc = S->sBC[bi];
      const float* td = S->sTD[bi];
      #pragma unroll 5
      for (int s = 0; s < TCH; ++s) {
        float2 Bv = *(const float2*)&bc[s * 36 + 2 * sg];
        float2 Cv = *(const float2*)&bc[s * 36 + 16 + 2 * sg];
        float2 t2 = *(const float2*)&td[s * 34 + 2 * ch];
        hst0 = fmaf(EXP2F(t2.x * Ac2x), hst0, t2.y * Bv.x);
        hst1 = fmaf(EXP2F(t2.x * Ac2y), hst1, t2.y * Bv.y);
        float cc2 = hst0 * Cv.x;
        cc2 = fmaf(hst1, Cv.y, cc2);
        cc2 = dpp_add<0xB1>(cc2);
        cc2 = dpp_add<0x4E>(cc2);
        cc2 = dpp_add<0x141>(cc2);
        if (sg == 0) S->sY[s * 16 + ch] = cc2;
      }
      asm volatile("s_waitcnt lgkmcnt(0)" ::: "memory");
      int row0 = bb * LSq + c * TCH;
      for (int i = lane; i < TCH * 4; i += 64) {
        int s = i >> 2, jj = (i & 3) | (cw << 2);
        float2 yp = *(const float2*)&S->sY[s * 16 + 2 * jj];
        uint up = S->sUZ[bi][s * 18 + jj];
        uint zp = S->sUZ[bi][s * 18 + 8 + jj];
        float y0 = (yp.x + S->sD[2 * jj]     * lo_f(up)) * lo_f(zp);
        float y1 = (yp.y + S->sD[2 * jj + 1] * hi_f(up)) * hi_f(zp);
        *(uint*)&y[(size_t)(row0 + s) * DIn + d0 + 2 * jj] =
            bbits(y0) | (bbits(y1) << 16);
      }
    } else if (c + 1 < LSq / TCH) {
      produce(c + 1, (c + 1) & 1, cw, 2);
    }
    __syncthreads();
  }
}

// ---------------- persistent megakernel: whole network, hand-rolled grid barrier ----------------
__global__ __launch_bounds__(256, 2) void k_mega(
    const float* __restrict__ fA, const short* __restrict__ wB,
    float* __restrict__ res, float* __restrict__ hbuf, float* __restrict__ hbuf2,
    float* __restrict__ xdb, bf16* __restrict__ hnB, bf16* __restrict__ uB,
    bf16* __restrict__ yB, bf16* __restrict__ xcB, bf16* __restrict__ zB,
    void* __restrict__ dOut, const void* probe) {
  __shared__ __align__(16) MegaSmem sm;
  int bid = blockIdx.x, tid = threadIdx.x;
  int ph = 0;

  for (int lay = 0; lay < NLa; ++lay) {
    // ---- norm (embed on layer 0) ----
    for (int row = bid; row < MROWS; row += NBLK)
      norm_row(row, hbuf, hbuf2, res, hnB,
               fA + F_LNW + lay * DMdl, fA + F_LNB + lay * DMdl, fA,
               lay == 0 ? 1 : 0, 0, lay == 0 ? 1 : 0, sm.nsh);
    grid_bar(ph);
    // ---- xz GEMM: M=3200, N=2048, K=512; 50 bands x 16 colb = 800 tiles (BJ=2) ----
    for (int tile = bid; tile < 800; tile += NBLK) {
      int band = tile >> 4, colb = tile & 15;
      gemm_tile<3, 2>(
          (const short*)hnB, wB + B_WIN + (size_t)lay * 2 * DIn * DMdl,
          xcB, zB, 2 * DIn, DMdl, DMdl, 0, band * 64, colb * 128, DIn, 0, true, &sm.g);
    }
    grid_bar(ph);
    // ---- conv + zero xdb ----
    for (int idx = bid * 256 + tid; idx < MROWS * (DIn / 2); idx += NBLK * 256) {
      int p = idx & (DIn / 2 - 1);
      int m = idx >> 9;
      int l = m % LSq, bb = m / LSq;
      int d = p * 2;
      const float* cwp = fA + F_CW + lay * DIn * 4;
      float a0 = fA[F_CB + lay * DIn + d];
      float a1 = fA[F_CB + lay * DIn + d + 1];
      #pragma unroll
      for (int k = 0; k < 4; ++k) {
        int ls = l + k - 3;
        if (ls >= 0) {
          uint xv = *(const uint*)&((const ushort*)xcB)[(size_t)(bb * LSq + ls) * DIn + d];
          a0 += lo_f(xv) * cwp[d * 4 + k];
          a1 += hi_f(xv) * cwp[(d + 1) * 4 + k];
        }
      }
      a0 = a0 / (1.f + __expf(-a0));
      a1 = a1 / (1.f + __expf(-a1));
      *(uint*)&((ushort*)uB)[(size_t)idx * 2] = bbits(a0) | (bbits(a1) << 16);
    }
    for (int i = bid * 256 + tid; i < MROWS * 16; i += NBLK * 256)
      ((f32x4*)xdb)[i] = (f32x4){0.f, 0.f, 0.f, 0.f};
    grid_bar(ph);
    // ---- xdb GEMM: M=3200, N=64, K=1024, split-K=8; 400 tiles (BJ=1) ----
    if (bid < 400) {
      int band = bid % 50, ks = bid / 50;
      gemm_tile<0, 1>(
          (const short*)uB, wB + B_WXP + (size_t)lay * 64 * DIn,
          xdb, nullptr, 64, DIn, 128, ks * 128, band * 64, 0, 0, 0, true, &sm.g);
    }
    grid_bar(ph);
    // ---- scan: 1024 units, 2 per block ----
    for (int L = bid; L < 1024; L += NBLK)
      scan_block(&sm.s, L, xdb, (const ushort*)uB, (const ushort*)zB,
                 wB + B_WDT, fA, lay, yB);
    grid_bar(ph);
    // ---- Wout GEMM: M=3200, N=512, K=1024, split-K=2 slabs; 400 tiles (BJ=2) ----
    if (bid < 400) {
      int band = bid % 50, r = bid / 50;    // r in 0..7
      int colb = r & 3, ks = r >> 2;
      gemm_tile<4, 2>(
          (const short*)yB, wB + B_WOUT + (size_t)lay * DMdl * DIn,
          hbuf, hbuf2, DMdl, DIn, 512, ks * 512, band * 64, colb * 128, 0, ks, true, &sm.g);
    }
    grid_bar(ph);
  }
  // ---- final RMS norm ----
  for (int row = bid; row < MROWS; row += NBLK)
    norm_row(row, hbuf, hbuf2, res, hnB, fA + F_FNW, fA + F_FNB, fA,
             0, 1, 0, sm.nsh);
  grid_bar(ph);
  // ---- head GEMM: M=3200, N=200, K=512; 100 tiles (BJ=2) ----
  bool f32o = probe_is_f32(probe);
  if (bid < 100) {
    int band = bid % 50, colb = bid / 50;
    gemm_tile<1, 2>(
        (const short*)hnB, wB + B_WHEAD, dOut, nullptr,
        CCl, DMdl, DMdl, 0, band * 64, colb * 128, 0, 0, f32o, &sm.g);
  }
}

extern "C" void kernel_launch(void* const* d_in, const int* in_sizes, int n_in,
                              void* d_out, int out_size, void* d_ws, size_t ws_size,
                              hipStream_t stream) {
  float* fA   = (float*)d_ws;
  short* wB   = (short*)(fA + F_TOT);
  float* acts = (float*)(wB + B_TOT);
  float* res  = acts;                          // 3200*512 f32
  float* hbuf = res  + (size_t)MROWS * DMdl;   // 3200*512 f32 (Wout partial slab 0)
  float* xdb  = hbuf + (size_t)MROWS * DMdl;   // 3200*64 f32 (split-K accumulator)
  bf16* hnB = (bf16*)(xdb + (size_t)MROWS * 64);          // 3200*512
  bf16* uB  = hnB + (size_t)MROWS * DMdl;                 // 3200*1024
  bf16* yB  = uB  + (size_t)MROWS * DIn;                  // 3200*1024
  bf16* xcB = yB  + (size_t)MROWS * DIn;                  // 3200*1024
  bf16* zB  = xcB + (size_t)MROWS * DIn;                  // 3200*1024
  float* hbuf2 = (float*)uB;     // Wout partial slab 1 aliases uB (dead at Wout time)

  k_convert<<<CVT_SMALL_BLK + CVT_WB_BLK, 256, 0, stream>>>(
      d_in[0], d_in[1], d_in[2], d_in[3], d_in[4], d_in[6], d_in[7],
      d_in[10], d_in[11], d_in[12], d_in[14], d_in[15],
      d_in[5], d_in[8], d_in[9], d_in[13], d_in[16], fA, wB);

  k_mega<<<NBLK, 256, 0, stream>>>(
      fA, wB, res, hbuf, hbuf2, xdb, hnB, uB, yB, xcB, zB, d_out, d_in[3]);
}